// Round 17
// baseline (3724.384 us; speedup 1.0000x reference)
//
#include <hip/hip_runtime.h>

#define TT 512
#define BATCH 256
#define HH 1024

typedef _Float16 half4  __attribute__((ext_vector_type(4)));
typedef _Float16 half8  __attribute__((ext_vector_type(8)));
typedef float    floatx4 __attribute__((ext_vector_type(4)));
typedef unsigned uint4v  __attribute__((ext_vector_type(4)));
typedef unsigned long long u64;
typedef u64 u64x2 __attribute__((ext_vector_type(2)));

// Agent-scope (MALL-coherent) 8B ops — fallback path + init.
__device__ __forceinline__ u64 hload(const _Float16* p) {
    return __hip_atomic_load((const u64*)p, __ATOMIC_RELAXED, __HIP_MEMORY_SCOPE_AGENT);
}
__device__ __forceinline__ void hstore(_Float16* p, u64 v) {
    __hip_atomic_store((u64*)p, v, __ATOMIC_RELAXED, __HIP_MEMORY_SCOPE_AGENT);
}

// ZERO-BARRIER independent-agent waves. Each of the group's 32 waves
// (8 wgs x 4 waves) runs the whole step privately:
//   poll 32 per-wave flags -> buffer_inv -> 32 plain b128 loads (whole
//   16x1024 tile; co-CU waves dedup via shared L1) -> 64 MFMAs -> epilogue
//   -> plain h' stores -> vmcnt(0) -> per-wave flag. y via per-wave
//   atomicAdd AFTER the flag (off critical path). No __syncthreads, no LDS.
// WAR-safe: flag=s+1 implies that wave's step-s reads completed (its stores
// data-depend on them); double buffer gives one step of slack.
// Per-wave buffer_inv only ever REMOVES L1 lines -> siblings stay correct.
// !FAST: same structure via agent-scope atomics (placement-agnostic).
template<bool FAST>
__device__ __forceinline__ void run_steps(
    int bbq, int jb, int tid, int w, int l15, int lhi,
    const float* __restrict__ x0, const float* __restrict__ targets,
    float* __restrict__ out,
    _Float16* __restrict__ hbuf0, _Float16* __restrict__ hbuf1,
    unsigned* __restrict__ flags,
    const half8 (&wfrag)[2][32],
    const float (&bias_r)[2][4], const float (&wih_r)[2][4],
    const float (&wout_r)[2][4], float bout)
{
    const int l   = tid & 63;
    const int g32 = bbq * 32;                 // this group's 32 flag slots
    const int fid = g32 + jb * 4 + w;         // this wave's flag

    for (int s = 0; s < TT; ++s) {
        const _Float16* hs = (s & 1) ? hbuf1 : hbuf0;
        _Float16*       hd = (s & 1) ? hbuf0 : hbuf1;

        // x prefetch before the poll (read-only input)
        const float xb = (s == 0) ? x0[bbq * 16 + l15]
                                  : targets[(size_t)(s - 1) * BATCH + bbq * 16 + l15];

        // ---- per-wave poll: all 32 producer waves of step s-1 done? ----
        const unsigned tgt = (unsigned)s;
        if (FAST) {
            for (;;) {
                uint4v f0 = *(volatile const uint4v*)&flags[g32 + 0];
                uint4v f1 = *(volatile const uint4v*)&flags[g32 + 4];
                uint4v f2 = *(volatile const uint4v*)&flags[g32 + 8];
                uint4v f3 = *(volatile const uint4v*)&flags[g32 + 12];
                uint4v f4 = *(volatile const uint4v*)&flags[g32 + 16];
                uint4v f5 = *(volatile const uint4v*)&flags[g32 + 20];
                uint4v f6 = *(volatile const uint4v*)&flags[g32 + 24];
                uint4v f7 = *(volatile const uint4v*)&flags[g32 + 28];
                unsigned m = f0[0];
                #define MIN4(v) { m = m<(v)[0]?m:(v)[0]; m = m<(v)[1]?m:(v)[1]; \
                                  m = m<(v)[2]?m:(v)[2]; m = m<(v)[3]?m:(v)[3]; }
                MIN4(f0) MIN4(f1) MIN4(f2) MIN4(f3)
                MIN4(f4) MIN4(f5) MIN4(f6) MIN4(f7)
                #undef MIN4
                if (m >= tgt) break;
            }
        } else {
            #pragma unroll 1
            for (int j = 0; j < 32; ++j)
                while (__hip_atomic_load(&flags[g32 + j], __ATOMIC_RELAXED,
                                         __HIP_MEMORY_SCOPE_AGENT) < tgt) {}
        }
        asm volatile("" ::: "memory");
        if (FAST)
            asm volatile("buffer_inv" ::: "memory");   // vL1-only invalidate
        __builtin_amdgcn_sched_barrier(0);             // pin loads below poll+inv

        // ---- B-frags: whole row straight from L2 (plain; L1 dedups waves) ----
        const _Float16* hrow = hs + (size_t)(bbq * 16 + l15) * HH + lhi * 8;
        floatx4 acc0 = {0,0,0,0}, acc1 = {0,0,0,0};
        #pragma unroll
        for (int tc = 0; tc < 2; ++tc) {               // 2 chunks of 16 (MLP=16)
            half8 bfrag[16];
            if (FAST) {
                #pragma unroll
                for (int t = 0; t < 16; ++t)
                    bfrag[t] = *(const half8*)(hrow + (tc * 16 + t) * 32);
            } else {
                #pragma unroll
                for (int t = 0; t < 16; ++t) {
                    u64x2 v;
                    v[0] = hload(hrow + (tc * 16 + t) * 32);
                    v[1] = hload(hrow + (tc * 16 + t) * 32 + 4);
                    bfrag[t] = __builtin_bit_cast(half8, v);
                }
            }
            #pragma unroll
            for (int t = 0; t < 16; ++t) {
                acc0 = __builtin_amdgcn_mfma_f32_16x16x32_f16(
                    wfrag[0][tc * 16 + t], bfrag[t], acc0, 0, 0, 0);
                acc1 = __builtin_amdgcn_mfma_f32_16x16x32_f16(
                    wfrag[1][tc * 16 + t], bfrag[t], acc1, 0, 0, 0);
            }
        }

        // ---- epilogue: lane owns batch b=l15, j = jb*128+(w+b2*4)*16+lhi*4+r
        float ht[2][4];
        #pragma unroll
        for (int b2 = 0; b2 < 2; ++b2) {
            const floatx4 a = b2 ? acc1 : acc0;
            #pragma unroll
            for (int r = 0; r < 4; ++r) {
                const float pp = a[r] + bias_r[b2][r] + xb * wih_r[b2][r];
                const float ex = __expf(2.0f * pp);
                ht[b2][r] = 1.0f - 2.0f / (ex + 1.0f);
            }
        }

        // ---- h' stores from registers (2 x 8B/lane, plain write-through) ----
        _Float16* hrd = hd + (size_t)(bbq * 16 + l15) * HH + jb * 128 + w * 16 + lhi * 4;
        #pragma unroll
        for (int b2 = 0; b2 < 2; ++b2) {
            half4 hv;
            hv[0] = (_Float16)ht[b2][0]; hv[1] = (_Float16)ht[b2][1];
            hv[2] = (_Float16)ht[b2][2]; hv[3] = (_Float16)ht[b2][3];
            if (FAST)
                *(half4*)(hrd + b2 * 64) = hv;
            else
                hstore(hrd + b2 * 64, __builtin_bit_cast(u64, hv));
        }

        // ---- y partial over this wave's 8 j's (shuffle while stores fly) ----
        float yv = 0.f;
        #pragma unroll
        for (int b2 = 0; b2 < 2; ++b2)
            #pragma unroll
            for (int r = 0; r < 4; ++r)
                yv += ht[b2][r] * wout_r[b2][r];
        yv += __shfl_xor(yv, 16);
        yv += __shfl_xor(yv, 32);

        asm volatile("s_waitcnt vmcnt(0)" ::: "memory");   // h' acked in L2
        if (l == 0) {
            if (FAST)
                *(volatile unsigned*)&flags[fid] = (unsigned)(s + 1);
            else
                __hip_atomic_store(&flags[fid], (unsigned)(s + 1),
                                   __ATOMIC_RELAXED, __HIP_MEMORY_SCOPE_AGENT);
        }
        // y off the critical path (after the flag)
        if (l < 16)
            atomicAdd(&out[(size_t)s * BATCH + bbq * 16 + l],
                      yv + ((jb == 0 && w == 0) ? bout : 0.f));
    }
}

// Grid: 128 wgs, 256 threads. bbq = wg&15, jb = wg>>4 -> group members share
// blockIdx mod 8 -> same XCD under round-robin. Colocation VERIFIED at runtime
// (HW_REG_XCC_ID exchange); L2-local fast path only when verified.
__global__ __launch_bounds__(256, 1)
void rnn_persistent(const float* __restrict__ x0,
                    const float* __restrict__ hidden0,
                    const float* __restrict__ targets,
                    const float* __restrict__ W_ih,
                    const float* __restrict__ W_hh,
                    const float* __restrict__ b_ih,
                    const float* __restrict__ b_hh,
                    const float* __restrict__ W_out,
                    const float* __restrict__ b_out,
                    float*       __restrict__ out,     // pre-zeroed
                    _Float16*    __restrict__ hbuf0,
                    _Float16*    __restrict__ hbuf1,
                    unsigned*    __restrict__ cnt,     // [16] agent counters (init)
                    unsigned*    __restrict__ flags,   // [16][32] per-wave step flags
                    unsigned*    __restrict__ xcds)    // [128] XCC ids
{
    const int wg  = blockIdx.x;
    const int bbq = wg & 15;
    const int jb  = wg >> 4;
    const int tid = threadIdx.x;
    const int w   = tid >> 6;
    const int l   = tid & 63;
    const int l15 = l & 15;
    const int lhi = l >> 4;

    __shared__ int fastflag;

    unsigned xcc;
    asm volatile("s_getreg_b32 %0, hwreg(HW_REG_XCC_ID)" : "=s"(xcc));

    // ---- one-time: W_hh A-frags. b2-block: rows jb*128+(w+b2*4)*16+l15,
    //      k = kk*32 + lhi*8  (full K, f16, 256 regs, ALL indices static) ----
    half8 wfrag[2][32];
    #pragma unroll
    for (int b2 = 0; b2 < 2; ++b2) {
        const float* wr = W_hh + (size_t)(jb * 128 + (w + b2 * 4) * 16 + l15) * HH + lhi * 8;
        #pragma unroll
        for (int kk = 0; kk < 32; ++kk) {
            floatx4 lo = *(const floatx4*)(wr + kk * 32);
            floatx4 hi = *(const floatx4*)(wr + kk * 32 + 4);
            half8 f;
            f[0]=(_Float16)lo[0]; f[1]=(_Float16)lo[1]; f[2]=(_Float16)lo[2]; f[3]=(_Float16)lo[3];
            f[4]=(_Float16)hi[0]; f[5]=(_Float16)hi[1]; f[6]=(_Float16)hi[2]; f[7]=(_Float16)hi[3];
            wfrag[b2][kk] = f;
        }
    }

    // per-lane epilogue constants for the 2 owned blocks
    float bias_r[2][4], wih_r[2][4], wout_r[2][4];
    #pragma unroll
    for (int b2 = 0; b2 < 2; ++b2)
        #pragma unroll
        for (int r = 0; r < 4; ++r) {
            const int j = jb * 128 + (w + b2 * 4) * 16 + lhi * 4 + r;
            bias_r[b2][r] = b_ih[j] + b_hh[j];
            wih_r[b2][r]  = W_ih[j];
            wout_r[b2][r] = W_out[j];
        }
    const float bout = b_out[0];

    // ---- init: fp32 hidden -> f16 hbuf0 (agent stores) + publish XCC id ----
    #pragma unroll
    for (int c = 0; c < 2; ++c) {
        const int q   = tid + c * 256;
        const int row = q >> 5, cc = q & 31;
        const float* s = hidden0 + (size_t)(bbq * 16 + row) * HH + jb * 128 + cc * 4;
        floatx4 f4 = *(const floatx4*)s;
        half4 h4;
        h4[0]=(_Float16)f4[0]; h4[1]=(_Float16)f4[1]; h4[2]=(_Float16)f4[2]; h4[3]=(_Float16)f4[3];
        hstore(hbuf0 + (size_t)(bbq * 16 + row) * HH + jb * 128 + cc * 4,
               __builtin_bit_cast(u64, h4));
    }
    if (tid == 0)
        __hip_atomic_store(&xcds[wg], xcc, __ATOMIC_RELAXED, __HIP_MEMORY_SCOPE_AGENT);
    asm volatile("s_waitcnt vmcnt(0)" ::: "memory");
    __syncthreads();
    if (tid == 0)
        __hip_atomic_fetch_add(&cnt[bbq], 1u, __ATOMIC_RELAXED, __HIP_MEMORY_SCOPE_AGENT);

    // ---- verdict: all 8 group members on one XCD? (also confirms init done) ----
    if (tid == 0) {
        while (__hip_atomic_load(&cnt[bbq], __ATOMIC_RELAXED,
                                 __HIP_MEMORY_SCOPE_AGENT) < 8u) {}
    }
    __syncthreads();
    if (tid < 64) {
        unsigned v = 0;
        if (l < 8)
            v = __hip_atomic_load(&xcds[(l << 4) + bbq], __ATOMIC_RELAXED,
                                  __HIP_MEMORY_SCOPE_AGENT);
        const unsigned v0 = __shfl(v, 0);
        const bool ok = (l >= 8) || (v == v0);
        const unsigned long long m = __ballot(ok);
        if (tid == 0) fastflag = (m == ~0ull) ? 1 : 0;
    }
    __syncthreads();
    const bool fast = (fastflag != 0);

    if (fast)
        run_steps<true >(bbq, jb, tid, w, l15, lhi, x0, targets, out,
                         hbuf0, hbuf1, flags, wfrag, bias_r, wih_r, wout_r, bout);
    else
        run_steps<false>(bbq, jb, tid, w, l15, lhi, x0, targets, out,
                         hbuf0, hbuf1, flags, wfrag, bias_r, wih_r, wout_r, bout);
}

extern "C" void kernel_launch(void* const* d_in, const int* in_sizes, int n_in,
                              void* d_out, int out_size, void* d_ws, size_t ws_size,
                              hipStream_t stream)
{
    const float* x0      = (const float*)d_in[0];
    const float* hidden0 = (const float*)d_in[1];
    const float* targets = (const float*)d_in[2];
    const float* W_ih    = (const float*)d_in[3];
    const float* W_hh    = (const float*)d_in[4];
    const float* b_ih    = (const float*)d_in[5];
    const float* b_hh    = (const float*)d_in[6];
    const float* W_out   = (const float*)d_in[7];
    const float* b_out   = (const float*)d_in[8];
    float* out = (float*)d_out;

    char* ws = (char*)d_ws;
    unsigned* cnt   = (unsigned*)ws;                          // [16]      @0
    unsigned* xcds  = (unsigned*)(ws + 256);                  // [128]     @256
    unsigned* flags = (unsigned*)(ws + 1024);                 // [16][32]  @1024 (2KB)
    _Float16* hbuf0 = (_Float16*)(ws + 4096);                 // 512 KB
    _Float16* hbuf1 = (_Float16*)(ws + 4096 + 512 * 1024);    // 512 KB

    hipMemsetAsync(ws, 0, 4096, stream);
    hipMemsetAsync(d_out, 0, (size_t)out_size * sizeof(float), stream);

    rnn_persistent<<<128, 256, 0, stream>>>(x0, hidden0, targets, W_ih, W_hh,
                                            b_ih, b_hh, W_out, b_out,
                                            out, hbuf0, hbuf1, cnt, flags, xcds);
}

// Round 18
// 1728.603 us; speedup vs baseline: 2.1546x; 2.1546x over previous
//
#include <hip/hip_runtime.h>

#define TT 512
#define BATCH 256
#define HH 1024

typedef _Float16 half4  __attribute__((ext_vector_type(4)));
typedef _Float16 half8  __attribute__((ext_vector_type(8)));
typedef float    floatx4 __attribute__((ext_vector_type(4)));
typedef unsigned uint4v  __attribute__((ext_vector_type(4)));
typedef unsigned long long u64;
typedef u64 u64x2 __attribute__((ext_vector_type(2)));

// Agent-scope (MALL-coherent) 8B ops — fallback path + init.
__device__ __forceinline__ u64 hload(const _Float16* p) {
    return __hip_atomic_load((const u64*)p, __ATOMIC_RELAXED, __HIP_MEMORY_SCOPE_AGENT);
}
__device__ __forceinline__ void hstore(_Float16* p, u64 v) {
    __hip_atomic_store((u64*)p, v, __ATOMIC_RELAXED, __HIP_MEMORY_SCOPE_AGENT);
}

// R16's staged datapath with ONE variable changed: stage loads are PLAIN
// CACHED (line-granular L1 fills -> 4x fewer L2 transactions than R16's
// sc0 16B requests, which bypass L1 and can't coalesce) + per-wave
// buffer_inv after the poll. Producer h' is in L2 when flags are visible
// (write-through L1 + vmcnt(0) ack), so every post-inv L1 fill is fresh;
// sibling invs only DROP lines (refill from fresh L2) — mechanics proven
// in R11. Everything else identical to R16 (best: 1815 us).
// !FAST: agent-scope atomics (placement-agnostic).
template<bool FAST>
__device__ __forceinline__ void run_steps(
    int bbq, int jb, int tid, int w, int l15, int lhi,
    const float* __restrict__ x0, const float* __restrict__ targets,
    float* __restrict__ out,
    _Float16* __restrict__ hbuf0, _Float16* __restrict__ hbuf1,
    unsigned* __restrict__ flags,
    const half8 (&wfrag)[2][32],
    const float (&bias_r)[2][4], const float (&wih_r)[2][4],
    const float (&wout_r)[2][4], float bout,
    float* y_red, char* hstage)
{
    const int l    = tid & 63;
    const int row4 = tid >> 4;                 // staged row (0..15)
    const int t15  = tid & 15;
    const int swz  = (l15 & 7) << 4;           // reader XOR (row = l15)
    const int wswz = (row4 & 7) << 4;          // writer XOR (row = row4)
    const char* lbase = hstage + l15 * 2048;
    char*       ldst  = hstage + row4 * 2048;

    for (int s = 0; s < TT; ++s) {
        const _Float16* hs = (s & 1) ? hbuf1 : hbuf0;
        _Float16*       hd = (s & 1) ? hbuf0 : hbuf1;

        // x prefetch before the poll (read-only input)
        const float xb = (s == 0) ? x0[bbq * 16 + l15]
                                  : targets[(size_t)(s - 1) * BATCH + bbq * 16 + l15];

        // ---- per-wave poll: every wave spins until all 8 producers at s ----
        const unsigned tgt = (unsigned)s;
        if (FAST) {
            for (;;) {
                uint4v a = *(volatile const uint4v*)&flags[bbq * 16];
                uint4v b = *(volatile const uint4v*)&flags[bbq * 16 + 4];
                unsigned m = a[0];
                m = m < a[1] ? m : a[1]; m = m < a[2] ? m : a[2];
                m = m < a[3] ? m : a[3]; m = m < b[0] ? m : b[0];
                m = m < b[1] ? m : b[1]; m = m < b[2] ? m : b[2];
                m = m < b[3] ? m : b[3];
                if (m >= tgt) break;
            }
        } else {
            #pragma unroll
            for (int j = 0; j < 8; ++j)
                while (__hip_atomic_load(&flags[bbq * 16 + j], __ATOMIC_RELAXED,
                                         __HIP_MEMORY_SCOPE_AGENT) < tgt) {}
        }
        asm volatile("" ::: "memory");
        if (FAST)
            asm volatile("buffer_inv" ::: "memory");   // vL1-only invalidate
        __builtin_amdgcn_sched_barrier(0);     // pin stage loads below poll+inv

        // ---- stage: 8 x 16B per thread, PLAIN CACHED (L2 line fills) ----
        const char* gsrc = (const char*)(hs + (size_t)bbq * 16 * HH)
                         + row4 * 2048 + t15 * 16;
        u64x2 sv[8];
        if (FAST) {
            #pragma unroll
            for (int j = 0; j < 8; ++j)
                sv[j] = *(const u64x2*)(gsrc + j * 256);
        } else {
            #pragma unroll
            for (int j = 0; j < 8; ++j) {
                const _Float16* q = (const _Float16*)(gsrc + j * 256);
                u64x2 v; v[0] = hload(q); v[1] = hload(q + 4);
                sv[j] = v;
            }
        }

        // ---- LDS write K-half-1 (j=0..3, bytes [0,1024) of each row) ----
        #pragma unroll
        for (int j = 0; j < 4; ++j)
            *(u64x2*)(ldst + ((t15 * 16 + j * 256) ^ wswz)) = sv[j];
        __syncthreads();                                   // (B1)

        // ---- MFMA half-1 (kt 0..15); loads j=4..7 drain underneath ----
        floatx4 acc0 = {0,0,0,0}, acc1 = {0,0,0,0};
        #pragma unroll
        for (int kt = 0; kt < 16; ++kt) {
            const half8 bf = *(const half8*)(lbase + ((kt * 64 + lhi * 16) ^ swz));
            acc0 = __builtin_amdgcn_mfma_f32_16x16x32_f16(wfrag[0][kt], bf, acc0, 0, 0, 0);
            acc1 = __builtin_amdgcn_mfma_f32_16x16x32_f16(wfrag[1][kt], bf, acc1, 0, 0, 0);
        }

        // ---- LDS write K-half-2 (j=4..7, bytes [1024,2048)) ----
        #pragma unroll
        for (int j = 4; j < 8; ++j)
            *(u64x2*)(ldst + ((t15 * 16 + j * 256) ^ wswz)) = sv[j];
        __syncthreads();                                   // (B2)

        // ---- MFMA half-2 (kt 16..31) ----
        #pragma unroll
        for (int kt = 16; kt < 32; ++kt) {
            const half8 bf = *(const half8*)(lbase + ((kt * 64 + lhi * 16) ^ swz));
            acc0 = __builtin_amdgcn_mfma_f32_16x16x32_f16(wfrag[0][kt], bf, acc0, 0, 0, 0);
            acc1 = __builtin_amdgcn_mfma_f32_16x16x32_f16(wfrag[1][kt], bf, acc1, 0, 0, 0);
        }

        // ---- epilogue: lane owns batch b=l15, j = jb*128+(w+b2*4)*16+lhi*4+r
        float ht[2][4];
        #pragma unroll
        for (int b2 = 0; b2 < 2; ++b2) {
            const floatx4 a = b2 ? acc1 : acc0;
            #pragma unroll
            for (int r = 0; r < 4; ++r) {
                const float pp = a[r] + bias_r[b2][r] + xb * wih_r[b2][r];
                const float ex = __expf(2.0f * pp);
                ht[b2][r] = 1.0f - 2.0f / (ex + 1.0f);
            }
        }

        // ---- h' stores DIRECT from registers (2 x 8B/lane) ----
        _Float16* hrd = hd + (size_t)(bbq * 16 + l15) * HH + jb * 128 + w * 16 + lhi * 4;
        #pragma unroll
        for (int b2 = 0; b2 < 2; ++b2) {
            half4 hv;
            hv[0] = (_Float16)ht[b2][0]; hv[1] = (_Float16)ht[b2][1];
            hv[2] = (_Float16)ht[b2][2]; hv[3] = (_Float16)ht[b2][3];
            if (FAST)
                *(half4*)(hrd + b2 * 64) = hv;             // plain: write-through to L2
            else
                hstore(hrd + b2 * 64, __builtin_bit_cast(u64, hv));
        }

        // ---- y partial (overlaps h'-store latency) ----
        float yv = 0.f;
        #pragma unroll
        for (int b2 = 0; b2 < 2; ++b2)
            #pragma unroll
            for (int r = 0; r < 4; ++r)
                yv += ht[b2][r] * wout_r[b2][r];
        yv += __shfl_xor(yv, 16);
        yv += __shfl_xor(yv, 32);
        if (l < 16) y_red[w * 16 + l] = yv;

        asm volatile("s_waitcnt vmcnt(0)" ::: "memory");   // stage reads + h' acked
        __syncthreads();                                   // (D)
        if (tid == 0) {
            if (FAST)
                *(volatile unsigned*)&flags[bbq * 16 + jb] = (unsigned)(s + 1);
            else
                __hip_atomic_store(&flags[bbq * 16 + jb], (unsigned)(s + 1),
                                   __ATOMIC_RELAXED, __HIP_MEMORY_SCOPE_AGENT);
        }
        // y finalization off the critical path (fire-and-forget atomics)
        if (tid >= 64 && tid < 80) {
            const int b = tid - 64;
            const float y = y_red[b] + y_red[16 + b] + y_red[32 + b] + y_red[48 + b] + bout;
            atomicAdd(&out[(size_t)s * BATCH + bbq * 16 + b], y);
        }
    }
}

// Grid: 128 wgs, 256 threads. bbq = wg&15, jb = wg>>4 -> group members share
// blockIdx mod 8 -> same XCD under round-robin. Colocation VERIFIED at runtime
// (HW_REG_XCC_ID exchange); L2-local fast path only when verified.
__global__ __launch_bounds__(256, 1)
void rnn_persistent(const float* __restrict__ x0,
                    const float* __restrict__ hidden0,
                    const float* __restrict__ targets,
                    const float* __restrict__ W_ih,
                    const float* __restrict__ W_hh,
                    const float* __restrict__ b_ih,
                    const float* __restrict__ b_hh,
                    const float* __restrict__ W_out,
                    const float* __restrict__ b_out,
                    float*       __restrict__ out,     // pre-zeroed
                    _Float16*    __restrict__ hbuf0,
                    _Float16*    __restrict__ hbuf1,
                    unsigned*    __restrict__ cnt,     // [16] agent counters (init)
                    unsigned*    __restrict__ flags,   // [16][16] step flags (64B/group)
                    unsigned*    __restrict__ xcds)    // [128] XCC ids
{
    const int wg  = blockIdx.x;
    const int bbq = wg & 15;
    const int jb  = wg >> 4;
    const int tid = threadIdx.x;
    const int w   = tid >> 6;
    const int l   = tid & 63;
    const int l15 = l & 15;
    const int lhi = l >> 4;

    __shared__ __align__(16) char  hstage[16 * 2048];  // 32 KB XOR-swizzled tile
    __shared__ __align__(16) float y_red[4 * 16];
    __shared__            int      fastflag;

    unsigned xcc;
    asm volatile("s_getreg_b32 %0, hwreg(HW_REG_XCC_ID)" : "=s"(xcc));

    // ---- one-time: W_hh A-frags. b2-block: rows jb*128+(w+b2*4)*16+l15,
    //      k = kk*32 + lhi*8  (full K, f16, 256 regs, ALL indices static) ----
    half8 wfrag[2][32];
    #pragma unroll
    for (int b2 = 0; b2 < 2; ++b2) {
        const float* wr = W_hh + (size_t)(jb * 128 + (w + b2 * 4) * 16 + l15) * HH + lhi * 8;
        #pragma unroll
        for (int kk = 0; kk < 32; ++kk) {
            floatx4 lo = *(const floatx4*)(wr + kk * 32);
            floatx4 hi = *(const floatx4*)(wr + kk * 32 + 4);
            half8 f;
            f[0]=(_Float16)lo[0]; f[1]=(_Float16)lo[1]; f[2]=(_Float16)lo[2]; f[3]=(_Float16)lo[3];
            f[4]=(_Float16)hi[0]; f[5]=(_Float16)hi[1]; f[6]=(_Float16)hi[2]; f[7]=(_Float16)hi[3];
            wfrag[b2][kk] = f;
        }
    }

    // per-lane epilogue constants for the 2 owned blocks
    float bias_r[2][4], wih_r[2][4], wout_r[2][4];
    #pragma unroll
    for (int b2 = 0; b2 < 2; ++b2)
        #pragma unroll
        for (int r = 0; r < 4; ++r) {
            const int j = jb * 128 + (w + b2 * 4) * 16 + lhi * 4 + r;
            bias_r[b2][r] = b_ih[j] + b_hh[j];
            wih_r[b2][r]  = W_ih[j];
            wout_r[b2][r] = W_out[j];
        }
    const float bout = (jb == 0) ? b_out[0] : 0.f;

    // ---- init: fp32 hidden -> f16 hbuf0 (agent stores) + publish XCC id ----
    #pragma unroll
    for (int c = 0; c < 2; ++c) {
        const int q   = tid + c * 256;
        const int row = q >> 5, cc = q & 31;
        const float* s = hidden0 + (size_t)(bbq * 16 + row) * HH + jb * 128 + cc * 4;
        floatx4 f4 = *(const floatx4*)s;
        half4 h4;
        h4[0]=(_Float16)f4[0]; h4[1]=(_Float16)f4[1]; h4[2]=(_Float16)f4[2]; h4[3]=(_Float16)f4[3];
        hstore(hbuf0 + (size_t)(bbq * 16 + row) * HH + jb * 128 + cc * 4,
               __builtin_bit_cast(u64, h4));
    }
    if (tid == 0)
        __hip_atomic_store(&xcds[wg], xcc, __ATOMIC_RELAXED, __HIP_MEMORY_SCOPE_AGENT);
    asm volatile("s_waitcnt vmcnt(0)" ::: "memory");
    __syncthreads();
    if (tid == 0)
        __hip_atomic_fetch_add(&cnt[bbq], 1u, __ATOMIC_RELAXED, __HIP_MEMORY_SCOPE_AGENT);

    // ---- verdict: all 8 group members on one XCD? (also confirms init done) ----
    if (tid == 0) {
        while (__hip_atomic_load(&cnt[bbq], __ATOMIC_RELAXED,
                                 __HIP_MEMORY_SCOPE_AGENT) < 8u) {}
    }
    __syncthreads();
    if (tid < 64) {
        unsigned v = 0;
        if (l < 8)
            v = __hip_atomic_load(&xcds[(l << 4) + bbq], __ATOMIC_RELAXED,
                                  __HIP_MEMORY_SCOPE_AGENT);
        const unsigned v0 = __shfl(v, 0);
        const bool ok = (l >= 8) || (v == v0);
        const unsigned long long m = __ballot(ok);
        if (tid == 0) fastflag = (m == ~0ull) ? 1 : 0;
    }
    __syncthreads();
    const bool fast = (fastflag != 0);

    if (fast)
        run_steps<true >(bbq, jb, tid, w, l15, lhi, x0, targets, out,
                         hbuf0, hbuf1, flags, wfrag,
                         bias_r, wih_r, wout_r, bout, y_red, hstage);
    else
        run_steps<false>(bbq, jb, tid, w, l15, lhi, x0, targets, out,
                         hbuf0, hbuf1, flags, wfrag,
                         bias_r, wih_r, wout_r, bout, y_red, hstage);
}

extern "C" void kernel_launch(void* const* d_in, const int* in_sizes, int n_in,
                              void* d_out, int out_size, void* d_ws, size_t ws_size,
                              hipStream_t stream)
{
    const float* x0      = (const float*)d_in[0];
    const float* hidden0 = (const float*)d_in[1];
    const float* targets = (const float*)d_in[2];
    const float* W_ih    = (const float*)d_in[3];
    const float* W_hh    = (const float*)d_in[4];
    const float* b_ih    = (const float*)d_in[5];
    const float* b_hh    = (const float*)d_in[6];
    const float* W_out   = (const float*)d_in[7];
    const float* b_out   = (const float*)d_in[8];
    float* out = (float*)d_out;

    char* ws = (char*)d_ws;
    unsigned* cnt   = (unsigned*)ws;                          // [16]      @0
    unsigned* flags = (unsigned*)(ws + 256);                  // [16][16]  @256 (1KB)
    unsigned* xcds  = (unsigned*)(ws + 2048);                 // [128]     @2048
    _Float16* hbuf0 = (_Float16*)(ws + 4096);                 // 512 KB
    _Float16* hbuf1 = (_Float16*)(ws + 4096 + 512 * 1024);    // 512 KB

    hipMemsetAsync(ws, 0, 4096, stream);
    hipMemsetAsync(d_out, 0, (size_t)out_size * sizeof(float), stream);

    rnn_persistent<<<128, 256, 0, stream>>>(x0, hidden0, targets, W_ih, W_hh,
                                            b_ih, b_hh, W_out, b_out,
                                            out, hbuf0, hbuf1, cnt, flags, xcds);
}